// Round 5
// baseline (243.858 us; speedup 1.0000x reference)
//
#include <hip/hip_runtime.h>
#include <hip/hip_cooperative_groups.h>
#include <math.h>

namespace cg = cooperative_groups;

#define B_SZ 2
#define HH 64
#define WW 64
#define DM 192
#define NS 16
#define RR 12
#define KD 4
#define LL (HH * WW)           // 4096
#define CPROJ (RR + 2 * NS)    // 44
#define CPAD 48
#define NCHc 64
#define CHc (LL / NCHc)        // 64
#define NBLK (B_SZ * KD * NCHc)  // 512
#define TLP 64                 // l-tile per proj block
#define LOG2E 1.44269504088896340736f
#define LN2F 0.69314718055994530942f

// component i (compile-time after unroll) of a float4 register array
#define RQF(arr, i) (((i) & 3) == 0 ? arr[(i) >> 2].x : ((i) & 3) == 1 ? arr[(i) >> 2].y \
                     : ((i) & 3) == 2 ? arr[(i) >> 2].z : arr[(i) >> 2].w)

// spatial index (row-major h*W+w) that scan position t of direction k touches
__device__ __forceinline__ int spatial_idx(int k, int t) {
    if (k == 0) return t;
    if (k == 1) return ((t & 63) << 6) | (t >> 6);          // t = w*H + h -> l = h*W + w
    if (k == 2) return LL - 1 - t;
    int tp = LL - 1 - t;
    return ((tp & 63) << 6) | (tp >> 6);
}

__device__ __forceinline__ void compute_dA(float dt, const float* Avl2, bool pw, float* dA) {
    if (pw) {
        float e1 = exp2f(dt * Avl2[0]);
        dA[0] = e1;
        dA[1] = e1 * e1;
        dA[2] = dA[1] * e1;
        dA[3] = dA[1] * dA[1];
        dA[4] = dA[3] * e1;
        dA[5] = dA[3] * dA[1];
        dA[6] = dA[3] * dA[2];
        dA[7] = dA[3] * dA[3];
        dA[8] = dA[7] * e1;
        dA[9] = dA[7] * dA[1];
        dA[10] = dA[7] * dA[2];
        dA[11] = dA[7] * dA[3];
        dA[12] = dA[7] * dA[4];
        dA[13] = dA[7] * dA[5];
        dA[14] = dA[7] * dA[6];
        dA[15] = dA[7] * dA[7];
    } else {
#pragma unroll
        for (int n = 0; n < NS; ++n) dA[n] = exp2f(dt * Avl2[n]);
    }
}

__device__ __forceinline__ void load_params(int kd, const float* __restrict__ dtw,
                                            const float* __restrict__ dtb,
                                            const float* __restrict__ Alogs,
                                            float* Wdt, float& bias, float* Avl2, bool& pw) {
#pragma unroll
    for (int r = 0; r < RR; ++r) Wdt[r] = dtw[(size_t)kd * RR + r];
    bias = dtb[kd];
#pragma unroll
    for (int n = 0; n < NS; ++n) Avl2[n] = -__expf(Alogs[(size_t)kd * NS + n]) * LOG2E;
    bool pws = true;
#pragma unroll
    for (int n = 0; n < NS; ++n)
        pws = pws && (fabsf(Avl2[n] - (float)(n + 1) * Avl2[0]) <= 1e-5f * fabsf(Avl2[n]) + 1e-30f);
    pw = (__all(pws ? 1 : 0) != 0);
}

// ---------------- phase 1: local chunk scan -> carry + aprod ----------------
__device__ __forceinline__ void scan_phase1_dev(
    int blk, int tid, const float* __restrict__ x, const float* __restrict__ xdbl,
    const float* __restrict__ dtw, const float* __restrict__ dtb,
    const float* __restrict__ Alogs,
    float* __restrict__ carry, float* __restrict__ aprod, float* xds) {
    const int chunk = blk % NCHc;
    const int bk = blk / NCHc;
    const int k = bk & 3, b = bk >> 2;
    const int d = tid;
    float Wdt[RR], bias, Avl2[NS];
    bool pw;
    load_params(k * DM + d, dtw, dtb, Alogs, Wdt, bias, Avl2, pw);

    // stage chunk's xdbl rows into LDS (768 float4, 4 per thread)
    {
        float4* dst = (float4*)xds;
        const float4* src = (const float4*)(xdbl + ((size_t)bk * LL + chunk * CHc) * CPAD);
#pragma unroll
        for (int i = 0; i < CHc * CPAD / 4 / DM; ++i)
            dst[tid + i * DM] = src[tid + i * DM];
    }
    __syncthreads();

    const float* xb = x + (size_t)b * LL * DM + d;
    float h[NS];
#pragma unroll
    for (int n = 0; n < NS; ++n) h[n] = 0.f;
    float dtsum = 0.f;

#pragma unroll 4
    for (int tt = 0; tt < CHc; ++tt) {
        const float4* row4 = (const float4*)(xds + tt * CPAD);
        float4 rq[7];
#pragma unroll
        for (int q = 0; q < 7; ++q) rq[q] = row4[q];    // dt inputs + B
        float z = bias;
#pragma unroll
        for (int r = 0; r < RR; ++r) z = fmaf(RQF(rq, r), Wdt[r], z);
        float dt = (z > 15.f) ? z : __log2f(1.f + exp2f(z * LOG2E)) * LN2F;
        int s = spatial_idx(k, chunk * CHc + tt);
        float xv = xb[(size_t)s * DM];
        float dtx = dt * xv;
        dtsum += dt;
        float dA[NS];
        compute_dA(dt, Avl2, pw, dA);
#pragma unroll
        for (int n = 0; n < NS; ++n)
            h[n] = fmaf(dA[n], h[n], dtx * RQF(rq, RR + n));
    }
    const size_t cbase = ((size_t)blk * DM + d) * NS;
#pragma unroll
    for (int n = 0; n < NS; ++n) {
        carry[cbase + n] = h[n];
        aprod[cbase + n] = exp2f(dtsum * Avl2[n]);      // prod of dA == exp(Av * sum dt)
    }
}

// ---------------- phase 2: inter-chunk sequential fixup ----------------
__device__ __forceinline__ void fix_dev(int idx, float* __restrict__ carry,
                                        const float* __restrict__ aprod) {
    int n = idx & (NS - 1);
    int dn = idx >> 4;
    int dd = dn % DM;
    int bkc = dn / DM;
    size_t base = ((size_t)bkc * NCHc * DM + dd) * NS + n;
    const size_t stride = (size_t)DM * NS;
    float hp = 0.f;
#pragma unroll 4
    for (int c = 0; c < NCHc; ++c) {
        size_t off = base + (size_t)c * stride;
        float P = aprod[off];
        float Cr = carry[off];
        carry[off] = hp;                 // state entering chunk c
        hp = fmaf(P, hp, Cr);
    }
}

// ---------------- phase 3: full scan with incoming state, emit y ----------------
template <bool STAGE>
__device__ __forceinline__ void scan_phase3_dev(
    int blk, int tid, const float* __restrict__ x, const float* __restrict__ xdbl,
    const float* __restrict__ dtw, const float* __restrict__ dtb,
    const float* __restrict__ Alogs, const float* __restrict__ Ds,
    const float* __restrict__ carry, float* __restrict__ ybuf4, float* xds) {
    const int chunk = blk % NCHc;
    const int bk = blk / NCHc;
    const int k = bk & 3, b = bk >> 2;
    const int d = tid;
    float Wdt[RR], bias, Avl2[NS];
    bool pw;
    load_params(k * DM + d, dtw, dtb, Alogs, Wdt, bias, Avl2, pw);
    const float Dval = Ds[k * DM + d];

    if (STAGE) {
        float4* dst = (float4*)xds;
        const float4* src = (const float4*)(xdbl + ((size_t)bk * LL + chunk * CHc) * CPAD);
#pragma unroll
        for (int i = 0; i < CHc * CPAD / 4 / DM; ++i)
            dst[tid + i * DM] = src[tid + i * DM];
        __syncthreads();
    }

    const float* xb = x + (size_t)b * LL * DM + d;
    const size_t cbase = ((size_t)blk * DM + d) * NS;
    float h[NS];
#pragma unroll
    for (int n = 0; n < NS; ++n) h[n] = carry[cbase + n];
    float* yk = ybuf4 + (size_t)k * ((size_t)B_SZ * LL * DM) + (size_t)b * LL * DM + d;

#pragma unroll 4
    for (int tt = 0; tt < CHc; ++tt) {
        const float4* row4 = (const float4*)(xds + tt * CPAD);
        float4 rq[11];
#pragma unroll
        for (int q = 0; q < 11; ++q) rq[q] = row4[q];   // dt inputs + B + C
        float z = bias;
#pragma unroll
        for (int r = 0; r < RR; ++r) z = fmaf(RQF(rq, r), Wdt[r], z);
        float dt = (z > 15.f) ? z : __log2f(1.f + exp2f(z * LOG2E)) * LN2F;
        int s = spatial_idx(k, chunk * CHc + tt);
        float xv = xb[(size_t)s * DM];
        float dtx = dt * xv;
        float dA[NS];
        compute_dA(dt, Avl2, pw, dA);
        float y = 0.f;
#pragma unroll
        for (int n = 0; n < NS; ++n) {
            h[n] = fmaf(dA[n], h[n], dtx * RQF(rq, RR + n));
            y = fmaf(h[n], RQF(rq, RR + NS + n), y);
        }
        yk[(size_t)s * DM] = y + Dval * xv;
    }
}

// ---------------- fused cooperative kernel (primary path) ----------------
__global__ __launch_bounds__(192) void scan_coop(
    const float* __restrict__ x, const float* __restrict__ xdbl,
    const float* __restrict__ dtw, const float* __restrict__ dtb,
    const float* __restrict__ Alogs, const float* __restrict__ Ds,
    float* __restrict__ carry, float* __restrict__ aprod, float* __restrict__ ybuf4) {
    __shared__ float xds[CHc * CPAD];        // 12 KB, persists across grid syncs
    cg::grid_group grid = cg::this_grid();
    scan_phase1_dev(blockIdx.x, threadIdx.x, x, xdbl, dtw, dtb, Alogs, carry, aprod, xds);
    grid.sync();
    if (blockIdx.x < 128)
        fix_dev(blockIdx.x * DM + threadIdx.x, carry, aprod);   // 128*192 = 24576 = B*K*D*N
    grid.sync();
    scan_phase3_dev<false>(blockIdx.x, threadIdx.x, x, xdbl, dtw, dtb, Alogs, Ds,
                           carry, ybuf4, xds);
}

// ---------------- split kernels (fallback path) ----------------
__global__ __launch_bounds__(192) void scan1_kernel(
    const float* __restrict__ x, const float* __restrict__ xdbl,
    const float* __restrict__ dtw, const float* __restrict__ dtb,
    const float* __restrict__ Alogs, float* __restrict__ carry, float* __restrict__ aprod) {
    __shared__ float xds[CHc * CPAD];
    scan_phase1_dev(blockIdx.x, threadIdx.x, x, xdbl, dtw, dtb, Alogs, carry, aprod, xds);
}

__global__ __launch_bounds__(192) void fix_kernel(float* __restrict__ carry,
                                                  const float* __restrict__ aprod) {
    fix_dev(blockIdx.x * DM + threadIdx.x, carry, aprod);
}

__global__ __launch_bounds__(192) void scan3_kernel(
    const float* __restrict__ x, const float* __restrict__ xdbl,
    const float* __restrict__ dtw, const float* __restrict__ dtb,
    const float* __restrict__ Alogs, const float* __restrict__ Ds,
    const float* __restrict__ carry, float* __restrict__ ybuf4) {
    __shared__ float xds[CHc * CPAD];
    scan_phase3_dev<true>(blockIdx.x, threadIdx.x, x, xdbl, dtw, dtb, Alogs, Ds,
                          carry, ybuf4, xds);
}

// ---------------- projection: xdbl[bk][l][c] = sum_d xs[b,k,d,l] * W[k,c,d] ----------------
__global__ __launch_bounds__(256) void proj_kernel(const float* __restrict__ x,
                                                   const float* __restrict__ xpw,
                                                   float* __restrict__ xdbl) {
    int blk = blockIdx.x;                    // B*K*(L/TLP) = 512
    int ltile = blk % (LL / TLP);
    int bk = blk / (LL / TLP);
    int k = bk & 3;
    int b = bk >> 2;
    int l0 = ltile * TLP;

    __shared__ float xt[DM * (TLP + 1)];     // transposed tile, stride 65 -> conflict-free reads

    {
        int li = threadIdx.x >> 2;
        int d0 = (threadIdx.x & 3) * 48;
        int s = spatial_idx(k, l0 + li);
        const float4* xr = (const float4*)(x + ((size_t)b * LL + s) * DM + d0);
#pragma unroll
        for (int q = 0; q < 12; ++q) {
            float4 v = xr[q];
            int d = d0 + q * 4;
            xt[(d + 0) * (TLP + 1) + li] = v.x;
            xt[(d + 1) * (TLP + 1) + li] = v.y;
            xt[(d + 2) * (TLP + 1) + li] = v.z;
            xt[(d + 3) * (TLP + 1) + li] = v.w;
        }
    }
    __syncthreads();

    int lane = threadIdx.x & 63;
    int wv = threadIdx.x >> 6;               // 0..3
    int c0 = __builtin_amdgcn_readfirstlane(wv * 11);
    const float* wk = xpw + (size_t)k * CPROJ * DM;

    float acc[11];
#pragma unroll
    for (int ci = 0; ci < 11; ++ci) acc[ci] = 0.f;

    for (int d = 0; d < DM; ++d) {
        float xv = xt[d * (TLP + 1) + lane];
#pragma unroll
        for (int ci = 0; ci < 11; ++ci)
            acc[ci] = fmaf(xv, wk[(size_t)(c0 + ci) * DM + d], acc[ci]);
    }
    float* orow = xdbl + ((size_t)bk * LL + l0 + lane) * CPAD;
#pragma unroll
    for (int ci = 0; ci < 11; ++ci) orow[c0 + ci] = acc[ci];
}

// ---------------- LayerNorm over D=192 with 4-direction merge, wave per row ----------------
__global__ __launch_bounds__(256) void ln_kernel(const float* __restrict__ ybuf,
                                                 const float* __restrict__ lnw,
                                                 const float* __restrict__ lnb,
                                                 float* __restrict__ out) {
    const size_t SEG = (size_t)B_SZ * LL * DM;
    int row = blockIdx.x * 4 + (threadIdx.x >> 6);   // B*L rows
    int lane = threadIdx.x & 63;
    const float* yr = ybuf + (size_t)row * DM;
    float v0 = 0.f, v1 = 0.f, v2 = 0.f;
#pragma unroll
    for (int kq = 0; kq < KD; ++kq) {
        const float* p = yr + kq * SEG;
        v0 += p[lane];
        v1 += p[lane + 64];
        v2 += p[lane + 128];
    }
    float s = v0 + v1 + v2;
    float sq = v0 * v0 + v1 * v1 + v2 * v2;
#pragma unroll
    for (int off = 32; off >= 1; off >>= 1) {
        s += __shfl_xor(s, off, 64);
        sq += __shfl_xor(sq, off, 64);
    }
    float mu = s * (1.f / DM);
    float var = sq * (1.f / DM) - mu * mu;
    float inv = rsqrtf(var + 1e-5f);
    float* orow = out + (size_t)row * DM;
    orow[lane]       = (v0 - mu) * inv * lnw[lane]       + lnb[lane];
    orow[lane + 64]  = (v1 - mu) * inv * lnw[lane + 64]  + lnb[lane + 64];
    orow[lane + 128] = (v2 - mu) * inv * lnw[lane + 128] + lnb[lane + 128];
}

extern "C" void kernel_launch(void* const* d_in, const int* in_sizes, int n_in,
                              void* d_out, int out_size, void* d_ws, size_t ws_size,
                              hipStream_t stream) {
    const float* x    = (const float*)d_in[0];
    const float* xpw  = (const float*)d_in[1];
    const float* dtw  = (const float*)d_in[2];
    const float* dtb  = (const float*)d_in[3];
    const float* Alog = (const float*)d_in[4];
    const float* Ds   = (const float*)d_in[5];
    const float* lnw  = (const float*)d_in[6];
    const float* lnb  = (const float*)d_in[7];
    float* out = (float*)d_out;

    const size_t F_XD = (size_t)B_SZ * KD * LL * CPAD;       // 1,572,864 floats (6.3 MB)
    const size_t F_CR = (size_t)B_SZ * KD * NCHc * DM * NS;  // 1,572,864 floats (6.3 MB)
    const size_t F_YB = (size_t)B_SZ * LL * DM;              // 1,572,864 floats (6.3 MB)

    float* ws    = (float*)d_ws;
    float* xdbl  = ws;
    float* carry = xdbl + F_XD;
    float* aprod = carry + F_CR;
    float* ybuf4 = aprod + F_CR;                             // 4 segments, 25.2 MB

    proj_kernel<<<B_SZ * KD * (LL / TLP), 256, 0, stream>>>(x, xpw, xdbl);

    void* args[] = { (void*)&x, (void*)&xdbl, (void*)&dtw, (void*)&dtb,
                     (void*)&Alog, (void*)&Ds, (void*)&carry, (void*)&aprod,
                     (void*)&ybuf4 };
    hipError_t cerr = hipLaunchCooperativeKernel((const void*)scan_coop, dim3(NBLK), dim3(DM),
                                                 args, 0, stream);
    if (cerr != hipSuccess) {
        (void)hipGetLastError();   // clear the failed-launch error; use split path
        scan1_kernel<<<NBLK, DM, 0, stream>>>(x, xdbl, dtw, dtb, Alog, carry, aprod);
        fix_kernel<<<128, DM, 0, stream>>>(carry, aprod);
        scan3_kernel<<<NBLK, DM, 0, stream>>>(x, xdbl, dtw, dtb, Alog, Ds, carry, ybuf4);
    }

    ln_kernel<<<(B_SZ * LL) / 4, 256, 0, stream>>>(ybuf4, lnw, lnb, out);
}